// Round 8
// baseline (184.743 us; speedup 1.0000x reference)
//
#include <hip/hip_runtime.h>
#include <cstddef>

#define NSTATES 32
#define SEQLEN 4096
#define NBATCH 256

#define F_LOG2E 1.44269504088896340736f
#define F_LN2   0.69314718055994530942f
#define F_NEG_HALF_LOG2PI -0.91893853320467274178f

#define EXP2F(x) __builtin_amdgcn_exp2f(x)
#define LOG2F(x) __builtin_amdgcn_logf(x)   // v_log_f32 == log2, despite the name
#define RCPF(x)  __builtin_amdgcn_rcpf(x)

typedef __attribute__((ext_vector_type(8)))  short short8;
typedef __attribute__((ext_vector_type(16))) float f32x16;

static __device__ __forceinline__ unsigned int pkbf(float lo, float hi) {
    unsigned int r;
    asm("v_cvt_pk_bf16_f32 %0, %1, %2" : "=v"(r) : "v"(lo), "v"(hi));
    return r;
}
static __device__ __forceinline__ void swp32(unsigned int& a, unsigned int& b) {
    asm volatile("v_permlane32_swap_b32 %0, %1" : "+v"(a), "+v"(b));
}
static __device__ __forceinline__ float xhalf_max(float v) {
    float a = v, b;
    asm("v_mov_b32 %0, %1" : "=v"(b) : "v"(v));
    asm volatile("v_permlane32_swap_b32 %0, %1" : "+v"(a), "+v"(b));
    return fmaxf(a, b);
}
static __device__ __forceinline__ float xhalf_add(float v) {
    float a = v, b;
    asm("v_mov_b32 %0, %1" : "=v"(b) : "v"(v));
    asm volatile("v_permlane32_swap_b32 %0, %1" : "+v"(a), "+v"(b));
    return a + b;
}
static __device__ __forceinline__ float vtmax(const f32x16& d) {
    return fmaxf(
      fmaxf(fmaxf(fmaxf(d[0],d[1]),fmaxf(d[2],d[3])), fmaxf(fmaxf(d[4],d[5]),fmaxf(d[6],d[7]))),
      fmaxf(fmaxf(fmaxf(d[8],d[9]),fmaxf(d[10],d[11])), fmaxf(fmaxf(d[12],d[13]),fmaxf(d[14],d[15]))));
}
static __device__ __forceinline__ float vtsum(const f32x16& d) {
    return ((((d[0]+d[1])+(d[2]+d[3])) + ((d[4]+d[5])+(d[6]+d[7])))
          + (((d[8]+d[9])+(d[10]+d[11])) + ((d[12]+d[13])+(d[14]+d[15]))));
}
// B-frags use the SAME (h,e)->k map as the A-frags, so k-permutation cancels.
static __device__ __forceinline__ void make_frags(const f32x16& q, short8& lo, short8& hi) {
    unsigned int X  = pkbf(q[0],  q[1]),  Z  = pkbf(q[2],  q[3]);
    unsigned int Y  = pkbf(q[4],  q[5]),  W  = pkbf(q[6],  q[7]);
    unsigned int X2 = pkbf(q[8],  q[9]),  Z2 = pkbf(q[10], q[11]);
    unsigned int Y2 = pkbf(q[12], q[13]), W2 = pkbf(q[14], q[15]);
    swp32(X, Y); swp32(Z, W); swp32(X2, Y2); swp32(Z2, W2);
    union { unsigned int w[4]; short8 s; } u;
    u.w[0] = X;  u.w[1] = Z;  u.w[2] = Y;  u.w[3] = W;  lo = u.s;
    u.w[0] = X2; u.w[1] = Z2; u.w[2] = Y2; u.w[3] = W2; hi = u.s;
}

#define MF_CONSTS_ALL                                                     \
    f32x16 muv, c0v, c1v, li2m;                                           \
    _Pragma("unroll")                                                     \
    for (int i = 0; i < 16; ++i) {                                        \
        int m = (i & 3) + ((i >> 2) << 3) + (h << 2);                     \
        float ls = log_sig[m];                                            \
        muv[i]  = means[m];                                               \
        c1v[i]  = -0.5f * expf(-2.0f * ls) * F_LOG2E;                     \
        c0v[i]  = (-ls + F_NEG_HALF_LOG2PI) * F_LOG2E;                    \
        li2m[i] = log_init[m] * F_LOG2E;                                  \
    }

#define MF_AFRAGS                                                         \
    const float* Ar = Amat + r * 32 + (h << 3);                           \
    float4 a0_ = *(const float4*)(Ar),      a1_ = *(const float4*)(Ar + 4);  \
    float4 a2_ = *(const float4*)(Ar + 16), a3_ = *(const float4*)(Ar + 20); \
    short8 alo, ahi;                                                      \
    {                                                                     \
        union { unsigned int ww[4]; short8 s; } ua;                       \
        ua.ww[0] = pkbf(a0_.x, a0_.y); ua.ww[1] = pkbf(a0_.z, a0_.w);     \
        ua.ww[2] = pkbf(a1_.x, a1_.y); ua.ww[3] = pkbf(a1_.z, a1_.w);     \
        alo = ua.s;                                                       \
        ua.ww[0] = pkbf(a2_.x, a2_.y); ua.ww[1] = pkbf(a2_.z, a2_.w);     \
        ua.ww[2] = pkbf(a3_.x, a3_.y); ua.ww[3] = pkbf(a3_.z, a3_.w);     \
        ahi = ua.s;                                                       \
    }

// stage obvs[row0+rr][tbase .. tbase+span) into xsw[t][rr]; tbase % 32 == 0
#define MF_STAGE(xsw, tbase, span)                                        \
    {                                                                     \
        const float* xr_ = obvs + (size_t)(row0 + r) * SEQLEN + (tbase);  \
        for (int tt = 4 * h; tt + 4 <= (span); tt += 8) {                 \
            float4 v_ = *(const float4*)(xr_ + tt);                       \
            xsw[tt + 0][r] = v_.x; xsw[tt + 1][r] = v_.y;                 \
            xsw[tt + 2][r] = v_.z; xsw[tt + 3][r] = v_.w;                 \
        }                                                                 \
        int tail0_ = (span) & ~3;                                         \
        for (int ii = lane; ii < ((span) - tail0_) * 32; ii += 64) {      \
            int tt_ = tail0_ + (ii >> 5), rr_ = ii & 31;                  \
            xsw[tt_][rr_] = obvs[(size_t)(row0 + rr_) * SEQLEN + (tbase) + tt_]; \
        }                                                                 \
        __threadfence_block();                                            \
    }

// K1: fused fwd+bwd recursions (round-5-verified bodies).
// fwd waves (wgid2<1024) write log2(f) f32 to lfdump (round-5 fdump layout).
// bwd waves write log2(b) f32 into out's own (row,t) 32-slot, fragment order.
__global__ __launch_bounds__(128, 2) void hmm_recurse2(
    const float* __restrict__ obvs, const float* __restrict__ log_init,
    const float* __restrict__ Amat, const float* __restrict__ means,
    const float* __restrict__ log_sig, float* __restrict__ lfdump,
    float* __restrict__ out)
{
    __shared__ float xs[2][128][32];
    const int tid = threadIdx.x;
    const int w = tid >> 6, lane = tid & 63, h = lane >> 5, r = lane & 31;
    const int wgid2 = blockIdx.x * 2 + w;
    const bool isfwd = (wgid2 < 1024);
    const int wgid = wgid2 & 1023;
    const int chunk = wgid & 127;
    const int rg = wgid >> 7;
    const int row0 = rg << 5;

    MF_CONSTS_ALL;
    MF_AFRAGS;
    const f32x16 zro = (f32x16)0.0f;
    float (*xsw)[32] = xs[w];

    if (isfwd) {
        const int t0 = chunk << 5, t1 = t0 + 32;
        const int ts = (t0 > 96) ? (t0 - 96) : 0;
        MF_STAGE(xsw, ts, t1 - ts);
        f32x16 qh;
        {
            float x0 = xsw[0][r];
            f32x16 cur;
#pragma unroll
            for (int i = 0; i < 16; ++i) {
                float dx = x0 - muv[i];
                cur[i] = fmaf(c1v[i] * dx, dx, c0v[i]) + (chunk == 0 ? li2m[i] : 0.0f);
                qh[i] = EXP2F(cur[i]);
            }
            if (chunk == 0)
                *(f32x16*)(lfdump + (((size_t)wgid * 32) << 10) + (lane << 4)) = cur;
        }
        for (int t = ts + 1; t < t1; ++t) {
            short8 blo, bhi; make_frags(qh, blo, bhi);
            f32x16 d = __builtin_amdgcn_mfma_f32_32x32x16_bf16(alo, blo, zro, 0, 0, 0);
            d = __builtin_amdgcn_mfma_f32_32x32x16_bf16(ahi, bhi, d, 0, 0, 0);
            float rs = RCPF(xhalf_max(vtmax(d)));
            float x = xsw[t - ts][r];
#pragma unroll
            for (int i = 0; i < 16; ++i) {
                float dx = x - muv[i];
                float e2 = fmaf(c1v[i] * dx, dx, c0v[i]);
                qh[i] = d[i] * rs * EXP2F(e2);
            }
            if (t >= t0) {
                f32x16 lg;
#pragma unroll
                for (int i = 0; i < 16; ++i) lg[i] = LOG2F(qh[i]);
                *(f32x16*)(lfdump + (((size_t)wgid * 32 + (t - t0)) << 10) + (lane << 4)) = lg;
            }
        }
    } else {
        const int t0 = chunk << 5, t1 = t0 + 32;
        const bool last = (chunk == 127);
        int tsb = last ? (SEQLEN - 1)
                       : ((t1 - 1 + 95 < SEQLEN - 1) ? (t1 - 1 + 95) : (SEQLEN - 1));
        MF_STAGE(xsw, t0, tsb - t0 + 1);
        float* lbrow = out + (size_t)(row0 + r) * (SEQLEN * NSTATES) + (h << 4);
        f32x16 bh;
        int tstart;
        if (last) {
            *(f32x16*)(lbrow + (size_t)(SEQLEN - 1) * NSTATES) = li2m;
            float lm = xhalf_max(vtmax(li2m));
#pragma unroll
            for (int i = 0; i < 16; ++i) bh[i] = EXP2F(li2m[i] - lm);
            tstart = SEQLEN - 2;
        } else {
#pragma unroll
            for (int i = 0; i < 16; ++i) bh[i] = 1.0f;
            tstart = tsb - 1;
        }
        for (int t = tstart; t >= t0; --t) {
            float x = xsw[t + 1 - t0][r];
            f32x16 wv;
#pragma unroll
            for (int i = 0; i < 16; ++i) {
                float dx = x - muv[i];
                float e2 = fmaf(c1v[i] * dx, dx, c0v[i]);
                wv[i] = bh[i] * EXP2F(e2);
            }
            short8 blo, bhi; make_frags(wv, blo, bhi);
            f32x16 d = __builtin_amdgcn_mfma_f32_32x32x16_bf16(alo, blo, zro, 0, 0, 0);
            d = __builtin_amdgcn_mfma_f32_32x32x16_bf16(ahi, bhi, d, 0, 0, 0);
            if (t < t1) {
                f32x16 lgb;
#pragma unroll
                for (int i = 0; i < 16; ++i) lgb[i] = LOG2F(d[i]);
                *(f32x16*)(lbrow + (size_t)t * NSTATES) = lgb;
            }
            float rs = RCPF(xhalf_max(vtmax(d)));
#pragma unroll
            for (int i = 0; i < 16; ++i) bh[i] = d[i] * rs;
        }
    }
}

// K2: combine g = lf + lb, softmax per (row,t), transpose via os tile, write
// natural order in place over the lb slots (same block region; data-dep safe).
__global__ __launch_bounds__(128) void hmm_combine2(
    const float* __restrict__ lfdump, float* __restrict__ out)
{
    __shared__ float os[2][32][128];
    const int tid = threadIdx.x;
    const int w = tid >> 6, lane = tid & 63, h = lane >> 5, r = lane & 31;
    const int wgid2 = blockIdx.x * 2 + w;          // [0,2048)
    const int rg = wgid2 >> 8, c16 = wgid2 & 255;
    const int row0 = rg << 5, tA = c16 << 4;
    const int xr4 = (r & 7) << 2;
    const float* lbrow = out + (size_t)(row0 + r) * (SEQLEN * NSTATES) + (h << 4);

    for (int tt = 0; tt < 16; ++tt) {
        int t = tA + tt;
        int wgf = (rg << 7) | (t >> 5), tl = t & 31;
        f32x16 fvv = *(const f32x16*)(lfdump + (((size_t)wgf * 32 + tl) << 10) + (lane << 4));
        f32x16 lgb = *(const f32x16*)(lbrow + (size_t)t * NSTATES);
        f32x16 g;
#pragma unroll
        for (int i = 0; i < 16; ++i) g[i] = fvv[i] + lgb[i];
        float mg = xhalf_max(vtmax(g));
        f32x16 p;
#pragma unroll
        for (int i = 0; i < 16; ++i) p[i] = EXP2F(g[i] - mg);
        float z = mg + LOG2F(xhalf_add(vtsum(p)));
#pragma unroll
        for (int i = 0; i < 16; ++i) g[i] = (g[i] - z) * F_LN2;
        float* orow = &os[w][r][0];
        int cb = ((t & 3) << 5) + (h << 2);
        float4 v0 = {g[0],  g[1],  g[2],  g[3]};
        float4 v1 = {g[4],  g[5],  g[6],  g[7]};
        float4 v2 = {g[8],  g[9],  g[10], g[11]};
        float4 v3 = {g[12], g[13], g[14], g[15]};
        *(float4*)(orow + ((cb + 0)  ^ xr4)) = v0;
        *(float4*)(orow + ((cb + 8)  ^ xr4)) = v1;
        *(float4*)(orow + ((cb + 16) ^ xr4)) = v2;
        *(float4*)(orow + ((cb + 24) ^ xr4)) = v3;
        if ((t & 3) == 3) {
            __threadfence_block();
            int q_ = lane & 3, r2 = lane >> 2;
#pragma unroll
            for (int p_ = 0; p_ < 2; ++p_) {
                int rf = p_ * 16 + r2;
                const float* orf = &os[w][rf][0];
                float* gb = out + (size_t)(row0 + rf) * (SEQLEN * NSTATES)
                                + (size_t)(t - 3) * NSTATES;
#pragma unroll
                for (int k_ = 0; k_ < 8; ++k_) {
                    int L = (k_ << 4) + (q_ << 2);
                    *(float4*)(gb + L) = *(const float4*)(orf + (L ^ ((rf & 7) << 2)));
                }
            }
            __threadfence_block();
        }
    }
}

extern "C" void kernel_launch(void* const* d_in, const int* in_sizes, int n_in,
                              void* d_out, int out_size, void* d_ws, size_t ws_size,
                              hipStream_t stream) {
    const float* obvs     = (const float*)d_in[0];
    const float* log_init = (const float*)d_in[1];
    const float* Amat     = (const float*)d_in[2];
    const float* means    = (const float*)d_in[3];
    const float* log_sig  = (const float*)d_in[4];
    float* out = (float*)d_out;
    float* lfdump = (float*)d_ws;   // needs NE*4 = 128 MiB (established: ws >= 192 MiB)

    hipLaunchKernelGGL(hmm_recurse2, dim3(1024), dim3(128), 0, stream,
                       obvs, log_init, Amat, means, log_sig, lfdump, out);
    hipLaunchKernelGGL(hmm_combine2, dim3(1024), dim3(128), 0, stream,
                       lfdump, out);
}

// Round 9
// 172.539 us; speedup vs baseline: 1.0707x; 1.0707x over previous
//
#include <hip/hip_runtime.h>
#include <cstddef>

#define NSTATES 32
#define SEQLEN 4096
#define NBATCH 256
#define CHUNK 16
#define HALO 48
#define NCHUNKS 256                 // SEQLEN / CHUNK
#define SPAN_MAX 64                 // CHUNK + HALO

#define F_LOG2E 1.44269504088896340736f
#define F_LN2   0.69314718055994530942f
#define F_NEG_HALF_LOG2PI -0.91893853320467274178f

#define EXP2F(x) __builtin_amdgcn_exp2f(x)
#define LOG2F(x) __builtin_amdgcn_logf(x)   // v_log_f32 == log2, despite the name
#define RCPF(x)  __builtin_amdgcn_rcpf(x)

typedef __attribute__((ext_vector_type(8)))  short short8;
typedef __attribute__((ext_vector_type(16))) float f32x16;

static __device__ __forceinline__ unsigned int pkbf(float lo, float hi) {
    unsigned int r;
    asm("v_cvt_pk_bf16_f32 %0, %1, %2" : "=v"(r) : "v"(lo), "v"(hi));
    return r;
}
static __device__ __forceinline__ void swp32(unsigned int& a, unsigned int& b) {
    asm volatile("v_permlane32_swap_b32 %0, %1" : "+v"(a), "+v"(b));
}
static __device__ __forceinline__ float xhalf_max(float v) {
    float a = v, b;
    asm("v_mov_b32 %0, %1" : "=v"(b) : "v"(v));
    asm volatile("v_permlane32_swap_b32 %0, %1" : "+v"(a), "+v"(b));
    return fmaxf(a, b);
}
static __device__ __forceinline__ float xhalf_add(float v) {
    float a = v, b;
    asm("v_mov_b32 %0, %1" : "=v"(b) : "v"(v));
    asm volatile("v_permlane32_swap_b32 %0, %1" : "+v"(a), "+v"(b));
    return a + b;
}
static __device__ __forceinline__ float vtmax(const f32x16& d) {
    return fmaxf(
      fmaxf(fmaxf(fmaxf(d[0],d[1]),fmaxf(d[2],d[3])), fmaxf(fmaxf(d[4],d[5]),fmaxf(d[6],d[7]))),
      fmaxf(fmaxf(fmaxf(d[8],d[9]),fmaxf(d[10],d[11])), fmaxf(fmaxf(d[12],d[13]),fmaxf(d[14],d[15]))));
}
static __device__ __forceinline__ float vtsum(const f32x16& d) {
    return ((((d[0]+d[1])+(d[2]+d[3])) + ((d[4]+d[5])+(d[6]+d[7])))
          + (((d[8]+d[9])+(d[10]+d[11])) + ((d[12]+d[13])+(d[14]+d[15]))));
}
// B-frags use the SAME (h,e)->k map as the A-frags, so k-permutation cancels.
static __device__ __forceinline__ void make_frags(const f32x16& q, short8& lo, short8& hi) {
    unsigned int X  = pkbf(q[0],  q[1]),  Z  = pkbf(q[2],  q[3]);
    unsigned int Y  = pkbf(q[4],  q[5]),  W  = pkbf(q[6],  q[7]);
    unsigned int X2 = pkbf(q[8],  q[9]),  Z2 = pkbf(q[10], q[11]);
    unsigned int Y2 = pkbf(q[12], q[13]), W2 = pkbf(q[14], q[15]);
    swp32(X, Y); swp32(Z, W); swp32(X2, Y2); swp32(Z2, W2);
    union { unsigned int w[4]; short8 s; } u;
    u.w[0] = X;  u.w[1] = Z;  u.w[2] = Y;  u.w[3] = W;  lo = u.s;
    u.w[0] = X2; u.w[1] = Z2; u.w[2] = Y2; u.w[3] = W2; hi = u.s;
}

#define MF_CONSTS_ALL                                                     \
    f32x16 muv, c0v, c1v, li2m;                                           \
    _Pragma("unroll")                                                     \
    for (int i = 0; i < 16; ++i) {                                        \
        int m = (i & 3) + ((i >> 2) << 3) + (h << 2);                     \
        float ls = log_sig[m];                                            \
        muv[i]  = means[m];                                               \
        c1v[i]  = -0.5f * expf(-2.0f * ls) * F_LOG2E;                     \
        c0v[i]  = (-ls + F_NEG_HALF_LOG2PI) * F_LOG2E;                    \
        li2m[i] = log_init[m] * F_LOG2E;                                  \
    }

#define MF_AFRAGS                                                         \
    const float* Ar = Amat + r * 32 + (h << 3);                           \
    float4 a0_ = *(const float4*)(Ar),      a1_ = *(const float4*)(Ar + 4);  \
    float4 a2_ = *(const float4*)(Ar + 16), a3_ = *(const float4*)(Ar + 20); \
    short8 alo, ahi;                                                      \
    {                                                                     \
        union { unsigned int ww[4]; short8 s; } ua;                       \
        ua.ww[0] = pkbf(a0_.x, a0_.y); ua.ww[1] = pkbf(a0_.z, a0_.w);     \
        ua.ww[2] = pkbf(a1_.x, a1_.y); ua.ww[3] = pkbf(a1_.z, a1_.w);     \
        alo = ua.s;                                                       \
        ua.ww[0] = pkbf(a2_.x, a2_.y); ua.ww[1] = pkbf(a2_.z, a2_.w);     \
        ua.ww[2] = pkbf(a3_.x, a3_.y); ua.ww[3] = pkbf(a3_.z, a3_.w);     \
        ahi = ua.s;                                                       \
    }

// stage obvs[row0+rr][tbase .. tbase+span) into xsw[t][rr]; tbase%4==0, span%4==0
#define MF_STAGE(xsw, tbase, span)                                        \
    {                                                                     \
        const float* xr_ = obvs + (size_t)(row0 + r) * SEQLEN + (tbase);  \
        for (int tt = 4 * h; tt + 4 <= (span); tt += 8) {                 \
            float4 v_ = *(const float4*)(xr_ + tt);                       \
            xsw[tt + 0][r] = v_.x; xsw[tt + 1][r] = v_.y;                 \
            xsw[tt + 2][r] = v_.z; xsw[tt + 3][r] = v_.w;                 \
        }                                                                 \
        __threadfence_block();                                            \
    }

// K1: fused fwd+bwd recursions; CHUNK=16, HALO=48, 4096 waves (4/SIMD).
// fwd waves (wgid2<2048) write log2(f) f32 to lfdump slot rg*4096+t.
// bwd waves write log2(b) f32 into out's own (row,t) 32-slot, fragment order.
__global__ __launch_bounds__(128, 4) void hmm_recurse3(
    const float* __restrict__ obvs, const float* __restrict__ log_init,
    const float* __restrict__ Amat, const float* __restrict__ means,
    const float* __restrict__ log_sig, float* __restrict__ lfdump,
    float* __restrict__ out)
{
    __shared__ float xs[2][SPAN_MAX][32];
    const int tid = threadIdx.x;
    const int w = tid >> 6, lane = tid & 63, h = lane >> 5, r = lane & 31;
    const int wgid2 = blockIdx.x * 2 + w;
    const bool isfwd = (wgid2 < 2048);
    const int wgid = wgid2 & 2047;
    const int chunk = wgid & (NCHUNKS - 1);
    const int rg = wgid >> 8;
    const int row0 = rg << 5;

    MF_CONSTS_ALL;
    MF_AFRAGS;
    const f32x16 zro = (f32x16)0.0f;
    float (*xsw)[32] = xs[w];

    if (isfwd) {
        const int t0 = chunk * CHUNK, t1 = t0 + CHUNK;
        const int ts = (t0 > HALO) ? (t0 - HALO) : 0;
        MF_STAGE(xsw, ts, t1 - ts);
        f32x16 qh;
        {
            float x0 = xsw[0][r];
            f32x16 cur;
#pragma unroll
            for (int i = 0; i < 16; ++i) {
                float dx = x0 - muv[i];
                cur[i] = fmaf(c1v[i] * dx, dx, c0v[i]) + (ts == 0 ? li2m[i] : 0.0f);
                qh[i] = EXP2F(cur[i]);
            }
            if (chunk == 0)
                *(f32x16*)(lfdump + (((size_t)rg * SEQLEN) << 10) + (lane << 4)) = cur;
        }
        for (int t = ts + 1; t < t1; ++t) {
            short8 blo, bhi; make_frags(qh, blo, bhi);
            f32x16 d = __builtin_amdgcn_mfma_f32_32x32x16_bf16(alo, blo, zro, 0, 0, 0);
            d = __builtin_amdgcn_mfma_f32_32x32x16_bf16(ahi, bhi, d, 0, 0, 0);
            float rs = RCPF(xhalf_max(vtmax(d)));
            float x = xsw[t - ts][r];
#pragma unroll
            for (int i = 0; i < 16; ++i) {
                float dx = x - muv[i];
                float e2 = fmaf(c1v[i] * dx, dx, c0v[i]);
                qh[i] = d[i] * rs * EXP2F(e2);
            }
            if (t >= t0) {
                f32x16 lg;
#pragma unroll
                for (int i = 0; i < 16; ++i) lg[i] = LOG2F(qh[i]);
                *(f32x16*)(lfdump + (((size_t)rg * SEQLEN + t) << 10) + (lane << 4)) = lg;
            }
        }
    } else {
        const int t0 = chunk * CHUNK, t1 = t0 + CHUNK;
        int tsb = t1 - 1 + HALO;
        if (tsb > SEQLEN - 1) tsb = SEQLEN - 1;
        MF_STAGE(xsw, t0, tsb - t0 + 1);
        float* lbrow = out + (size_t)(row0 + r) * (SEQLEN * NSTATES) + (h << 4);
        f32x16 bh;
        if (tsb == SEQLEN - 1) {
            // exact init from b(T-1) = exp2(li2m) (chunks 252..255)
            if (chunk == NCHUNKS - 1)
                *(f32x16*)(lbrow + (size_t)(SEQLEN - 1) * NSTATES) = li2m;
            float lm = xhalf_max(vtmax(li2m));
#pragma unroll
            for (int i = 0; i < 16; ++i) bh[i] = EXP2F(li2m[i] - lm);
        } else {
#pragma unroll
            for (int i = 0; i < 16; ++i) bh[i] = 1.0f;
        }
        for (int t = tsb - 1; t >= t0; --t) {
            float x = xsw[t + 1 - t0][r];
            f32x16 wv;
#pragma unroll
            for (int i = 0; i < 16; ++i) {
                float dx = x - muv[i];
                float e2 = fmaf(c1v[i] * dx, dx, c0v[i]);
                wv[i] = bh[i] * EXP2F(e2);
            }
            short8 blo, bhi; make_frags(wv, blo, bhi);
            f32x16 d = __builtin_amdgcn_mfma_f32_32x32x16_bf16(alo, blo, zro, 0, 0, 0);
            d = __builtin_amdgcn_mfma_f32_32x32x16_bf16(ahi, bhi, d, 0, 0, 0);
            if (t < t1) {
                f32x16 lgb;
#pragma unroll
                for (int i = 0; i < 16; ++i) lgb[i] = LOG2F(d[i]);
                *(f32x16*)(lbrow + (size_t)t * NSTATES) = lgb;
            }
            float rs = RCPF(xhalf_max(vtmax(d)));
#pragma unroll
            for (int i = 0; i < 16; ++i) bh[i] = d[i] * rs;
        }
    }
}

// K2: combine g = lf + lb, softmax per (row,t), transpose via os tile, write
// natural order in place over the lb slots (round-8 verified, layout-identical).
__global__ __launch_bounds__(128) void hmm_combine2(
    const float* __restrict__ lfdump, float* __restrict__ out)
{
    __shared__ float os[2][32][128];
    const int tid = threadIdx.x;
    const int w = tid >> 6, lane = tid & 63, h = lane >> 5, r = lane & 31;
    const int wgid2 = blockIdx.x * 2 + w;          // [0,2048)
    const int rg = wgid2 >> 8, c16 = wgid2 & 255;
    const int row0 = rg << 5, tA = c16 << 4;
    const int xr4 = (r & 7) << 2;
    const float* lbrow = out + (size_t)(row0 + r) * (SEQLEN * NSTATES) + (h << 4);

    for (int tt = 0; tt < 16; ++tt) {
        int t = tA + tt;
        f32x16 fvv = *(const f32x16*)(lfdump + (((size_t)rg * SEQLEN + t) << 10) + (lane << 4));
        f32x16 lgb = *(const f32x16*)(lbrow + (size_t)t * NSTATES);
        f32x16 g;
#pragma unroll
        for (int i = 0; i < 16; ++i) g[i] = fvv[i] + lgb[i];
        float mg = xhalf_max(vtmax(g));
        f32x16 p;
#pragma unroll
        for (int i = 0; i < 16; ++i) p[i] = EXP2F(g[i] - mg);
        float z = mg + LOG2F(xhalf_add(vtsum(p)));
#pragma unroll
        for (int i = 0; i < 16; ++i) g[i] = (g[i] - z) * F_LN2;
        float* orow = &os[w][r][0];
        int cb = ((t & 3) << 5) + (h << 2);
        float4 v0 = {g[0],  g[1],  g[2],  g[3]};
        float4 v1 = {g[4],  g[5],  g[6],  g[7]};
        float4 v2 = {g[8],  g[9],  g[10], g[11]};
        float4 v3 = {g[12], g[13], g[14], g[15]};
        *(float4*)(orow + ((cb + 0)  ^ xr4)) = v0;
        *(float4*)(orow + ((cb + 8)  ^ xr4)) = v1;
        *(float4*)(orow + ((cb + 16) ^ xr4)) = v2;
        *(float4*)(orow + ((cb + 24) ^ xr4)) = v3;
        if ((t & 3) == 3) {
            __threadfence_block();
            int q_ = lane & 3, r2 = lane >> 2;
#pragma unroll
            for (int p_ = 0; p_ < 2; ++p_) {
                int rf = p_ * 16 + r2;
                const float* orf = &os[w][rf][0];
                float* gb = out + (size_t)(row0 + rf) * (SEQLEN * NSTATES)
                                + (size_t)(t - 3) * NSTATES;
#pragma unroll
                for (int k_ = 0; k_ < 8; ++k_) {
                    int L = (k_ << 4) + (q_ << 2);
                    *(float4*)(gb + L) = *(const float4*)(orf + (L ^ ((rf & 7) << 2)));
                }
            }
            __threadfence_block();
        }
    }
}

extern "C" void kernel_launch(void* const* d_in, const int* in_sizes, int n_in,
                              void* d_out, int out_size, void* d_ws, size_t ws_size,
                              hipStream_t stream) {
    const float* obvs     = (const float*)d_in[0];
    const float* log_init = (const float*)d_in[1];
    const float* Amat     = (const float*)d_in[2];
    const float* means    = (const float*)d_in[3];
    const float* log_sig  = (const float*)d_in[4];
    float* out = (float*)d_out;
    float* lfdump = (float*)d_ws;   // 128 MiB (ws >= 192 MiB established in r6/7)

    hipLaunchKernelGGL(hmm_recurse3, dim3(2048), dim3(128), 0, stream,
                       obvs, log_init, Amat, means, log_sig, lfdump, out);
    hipLaunchKernelGGL(hmm_combine2, dim3(1024), dim3(128), 0, stream,
                       lfdump, out);
}

// Round 10
// 168.279 us; speedup vs baseline: 1.0978x; 1.0253x over previous
//
#include <hip/hip_runtime.h>
#include <cstddef>

#define NSTATES 32
#define SEQLEN 4096
#define NBATCH 256
#define CHUNK 16
#define HALO 32
#define NCHUNKS 256                 // SEQLEN / CHUNK
#define SPAN_MAX 48                 // CHUNK + HALO

#define F_LOG2E 1.44269504088896340736f
#define F_LN2   0.69314718055994530942f
#define F_NEG_HALF_LOG2PI -0.91893853320467274178f
#define SCALE60 1.152921504606847e18f   // 2^60, keeps p = f*b out of denormal range

#define EXP2F(x) __builtin_amdgcn_exp2f(x)
#define LOG2F(x) __builtin_amdgcn_logf(x)   // v_log_f32 == log2, despite the name
#define RCPF(x)  __builtin_amdgcn_rcpf(x)

typedef __attribute__((ext_vector_type(8)))  short short8;
typedef __attribute__((ext_vector_type(16))) float f32x16;

static __device__ __forceinline__ unsigned int pkbf(float lo, float hi) {
    unsigned int r;
    asm("v_cvt_pk_bf16_f32 %0, %1, %2" : "=v"(r) : "v"(lo), "v"(hi));
    return r;
}
static __device__ __forceinline__ void swp32(unsigned int& a, unsigned int& b) {
    asm volatile("v_permlane32_swap_b32 %0, %1" : "+v"(a), "+v"(b));
}
static __device__ __forceinline__ float xhalf_max(float v) {
    float a = v, b;
    asm("v_mov_b32 %0, %1" : "=v"(b) : "v"(v));
    asm volatile("v_permlane32_swap_b32 %0, %1" : "+v"(a), "+v"(b));
    return fmaxf(a, b);
}
static __device__ __forceinline__ float xhalf_add(float v) {
    float a = v, b;
    asm("v_mov_b32 %0, %1" : "=v"(b) : "v"(v));
    asm volatile("v_permlane32_swap_b32 %0, %1" : "+v"(a), "+v"(b));
    return a + b;
}
static __device__ __forceinline__ float vtmax(const f32x16& d) {
    return fmaxf(
      fmaxf(fmaxf(fmaxf(d[0],d[1]),fmaxf(d[2],d[3])), fmaxf(fmaxf(d[4],d[5]),fmaxf(d[6],d[7]))),
      fmaxf(fmaxf(fmaxf(d[8],d[9]),fmaxf(d[10],d[11])), fmaxf(fmaxf(d[12],d[13]),fmaxf(d[14],d[15]))));
}
static __device__ __forceinline__ float vtsum(const f32x16& d) {
    return ((((d[0]+d[1])+(d[2]+d[3])) + ((d[4]+d[5])+(d[6]+d[7])))
          + (((d[8]+d[9])+(d[10]+d[11])) + ((d[12]+d[13])+(d[14]+d[15]))));
}
// B-frags use the SAME (h,e)->k map as the A-frags, so k-permutation cancels.
static __device__ __forceinline__ void make_frags(const f32x16& q, short8& lo, short8& hi) {
    unsigned int X  = pkbf(q[0],  q[1]),  Z  = pkbf(q[2],  q[3]);
    unsigned int Y  = pkbf(q[4],  q[5]),  W  = pkbf(q[6],  q[7]);
    unsigned int X2 = pkbf(q[8],  q[9]),  Z2 = pkbf(q[10], q[11]);
    unsigned int Y2 = pkbf(q[12], q[13]), W2 = pkbf(q[14], q[15]);
    swp32(X, Y); swp32(Z, W); swp32(X2, Y2); swp32(Z2, W2);
    union { unsigned int w[4]; short8 s; } u;
    u.w[0] = X;  u.w[1] = Z;  u.w[2] = Y;  u.w[3] = W;  lo = u.s;
    u.w[0] = X2; u.w[1] = Z2; u.w[2] = Y2; u.w[3] = W2; hi = u.s;
}

#define MF_CONSTS_ALL                                                     \
    f32x16 muv, c0v, c1v, li2m;                                           \
    _Pragma("unroll")                                                     \
    for (int i = 0; i < 16; ++i) {                                        \
        int m = (i & 3) + ((i >> 2) << 3) + (h << 2);                     \
        float ls = log_sig[m];                                            \
        muv[i]  = means[m];                                               \
        c1v[i]  = -0.5f * expf(-2.0f * ls) * F_LOG2E;                     \
        c0v[i]  = (-ls + F_NEG_HALF_LOG2PI) * F_LOG2E;                    \
        li2m[i] = log_init[m] * F_LOG2E;                                  \
    }

#define MF_AFRAGS                                                         \
    const float* Ar = Amat + r * 32 + (h << 3);                           \
    float4 a0_ = *(const float4*)(Ar),      a1_ = *(const float4*)(Ar + 4);  \
    float4 a2_ = *(const float4*)(Ar + 16), a3_ = *(const float4*)(Ar + 20); \
    short8 alo, ahi;                                                      \
    {                                                                     \
        union { unsigned int ww[4]; short8 s; } ua;                       \
        ua.ww[0] = pkbf(a0_.x, a0_.y); ua.ww[1] = pkbf(a0_.z, a0_.w);     \
        ua.ww[2] = pkbf(a1_.x, a1_.y); ua.ww[3] = pkbf(a1_.z, a1_.w);     \
        alo = ua.s;                                                       \
        ua.ww[0] = pkbf(a2_.x, a2_.y); ua.ww[1] = pkbf(a2_.z, a2_.w);     \
        ua.ww[2] = pkbf(a3_.x, a3_.y); ua.ww[3] = pkbf(a3_.z, a3_.w);     \
        ahi = ua.s;                                                       \
    }

// stage obvs[row0+rr][tbase .. tbase+span) into xsw[t][rr]; tbase%4==0, span%4==0
#define MF_STAGE(xsw, tbase, span)                                        \
    {                                                                     \
        const float* xr_ = obvs + (size_t)(row0 + r) * SEQLEN + (tbase);  \
        for (int tt = 4 * h; tt + 4 <= (span); tt += 8) {                 \
            float4 v_ = *(const float4*)(xr_ + tt);                       \
            xsw[tt + 0][r] = v_.x; xsw[tt + 1][r] = v_.y;                 \
            xsw[tt + 2][r] = v_.z; xsw[tt + 3][r] = v_.w;                 \
        }                                                                 \
        __threadfence_block();                                            \
    }

// K1: fused fwd+bwd recursions; CHUNK=16, HALO=32, 4096 waves (4/SIMD).
// fwd waves (wgid2<2048) write LINEAR max-normalized f (x 2^60) to lfdump.
// bwd waves write LINEAR max-normalized b (=bh, free) into out's (row,t) slot.
__global__ __launch_bounds__(128, 4) void hmm_recurse4(
    const float* __restrict__ obvs, const float* __restrict__ log_init,
    const float* __restrict__ Amat, const float* __restrict__ means,
    const float* __restrict__ log_sig, float* __restrict__ lfdump,
    float* __restrict__ out)
{
    __shared__ float xs[2][SPAN_MAX][32];
    const int tid = threadIdx.x;
    const int w = tid >> 6, lane = tid & 63, h = lane >> 5, r = lane & 31;
    const int wgid2 = blockIdx.x * 2 + w;
    const bool isfwd = (wgid2 < 2048);
    const int wgid = wgid2 & 2047;
    const int chunk = wgid & (NCHUNKS - 1);
    const int rg = wgid >> 8;
    const int row0 = rg << 5;

    MF_CONSTS_ALL;
    MF_AFRAGS;
    const f32x16 zro = (f32x16)0.0f;
    float (*xsw)[32] = xs[w];

    if (isfwd) {
        const int t0 = chunk * CHUNK, t1 = t0 + CHUNK;
        const int ts = (t0 > HALO) ? (t0 - HALO) : 0;
        MF_STAGE(xsw, ts, t1 - ts);
        f32x16 qh;
        {
            float x0 = xsw[0][r];
#pragma unroll
            for (int i = 0; i < 16; ++i) {
                float dx = x0 - muv[i];
                float cur = fmaf(c1v[i] * dx, dx, c0v[i]) + (ts == 0 ? li2m[i] : 0.0f);
                qh[i] = EXP2F(cur);
            }
            if (chunk == 0) {
                float s2 = RCPF(xhalf_max(vtmax(qh))) * SCALE60;
                f32x16 fv;
#pragma unroll
                for (int i = 0; i < 16; ++i) fv[i] = qh[i] * s2;
                *(f32x16*)(lfdump + (((size_t)rg * SEQLEN) << 10) + (lane << 4)) = fv;
            }
        }
        for (int t = ts + 1; t < t1; ++t) {
            short8 blo, bhi; make_frags(qh, blo, bhi);
            f32x16 d = __builtin_amdgcn_mfma_f32_32x32x16_bf16(alo, blo, zro, 0, 0, 0);
            d = __builtin_amdgcn_mfma_f32_32x32x16_bf16(ahi, bhi, d, 0, 0, 0);
            float rs = RCPF(xhalf_max(vtmax(d)));
            float x = xsw[t - ts][r];
#pragma unroll
            for (int i = 0; i < 16; ++i) {
                float dx = x - muv[i];
                float e2 = fmaf(c1v[i] * dx, dx, c0v[i]);
                qh[i] = d[i] * rs * EXP2F(e2);
            }
            if (t >= t0) {
                float s2 = RCPF(xhalf_max(vtmax(qh))) * SCALE60;
                f32x16 fv;
#pragma unroll
                for (int i = 0; i < 16; ++i) fv[i] = qh[i] * s2;
                *(f32x16*)(lfdump + (((size_t)rg * SEQLEN + t) << 10) + (lane << 4)) = fv;
            }
        }
    } else {
        const int t0 = chunk * CHUNK, t1 = t0 + CHUNK;
        int tsb = t1 - 1 + HALO;
        if (tsb > SEQLEN - 1) tsb = SEQLEN - 1;
        MF_STAGE(xsw, t0, tsb - t0 + 1);
        float* lbrow = out + (size_t)(row0 + r) * (SEQLEN * NSTATES) + (h << 4);
        f32x16 bh;
        if (tsb == SEQLEN - 1) {
            // exact init from b(T-1) = exp2(li2m), max-normalized
            float lm = xhalf_max(vtmax(li2m));
#pragma unroll
            for (int i = 0; i < 16; ++i) bh[i] = EXP2F(li2m[i] - lm);
            if (chunk == NCHUNKS - 1)
                *(f32x16*)(lbrow + (size_t)(SEQLEN - 1) * NSTATES) = bh;
        } else {
#pragma unroll
            for (int i = 0; i < 16; ++i) bh[i] = 1.0f;
        }
        for (int t = tsb - 1; t >= t0; --t) {
            float x = xsw[t + 1 - t0][r];
            f32x16 wv;
#pragma unroll
            for (int i = 0; i < 16; ++i) {
                float dx = x - muv[i];
                float e2 = fmaf(c1v[i] * dx, dx, c0v[i]);
                wv[i] = bh[i] * EXP2F(e2);
            }
            short8 blo, bhi; make_frags(wv, blo, bhi);
            f32x16 d = __builtin_amdgcn_mfma_f32_32x32x16_bf16(alo, blo, zro, 0, 0, 0);
            d = __builtin_amdgcn_mfma_f32_32x32x16_bf16(ahi, bhi, d, 0, 0, 0);
            float rs = RCPF(xhalf_max(vtmax(d)));
#pragma unroll
            for (int i = 0; i < 16; ++i) bh[i] = d[i] * rs;
            if (t < t1)
                *(f32x16*)(lbrow + (size_t)t * NSTATES) = bh;   // linear, normalized
        }
    }
}

// K2: p = f*b (linear), z = log2(sum), out = (log2 p - z)*ln2; transpose via os
// tile, write natural order in place over the lb slots. 4096 waves, 8 t's each.
__global__ __launch_bounds__(128) void hmm_combine3(
    const float* __restrict__ lfdump, float* __restrict__ out)
{
    __shared__ float os[2][32][128];
    const int tid = threadIdx.x;
    const int w = tid >> 6, lane = tid & 63, h = lane >> 5, r = lane & 31;
    const int wgid2 = blockIdx.x * 2 + w;          // [0,4096)
    const int rg = wgid2 >> 9, c8 = wgid2 & 511;
    const int row0 = rg << 5, tA = c8 << 3;
    const int xr4 = (r & 7) << 2;
    const float* lbrow = out + (size_t)(row0 + r) * (SEQLEN * NSTATES) + (h << 4);

    for (int tt = 0; tt < 8; ++tt) {
        int t = tA + tt;
        f32x16 fvv = *(const f32x16*)(lfdump + (((size_t)rg * SEQLEN + t) << 10) + (lane << 4));
        f32x16 lgb = *(const f32x16*)(lbrow + (size_t)t * NSTATES);
        f32x16 p;
#pragma unroll
        for (int i = 0; i < 16; ++i) p[i] = fvv[i] * lgb[i];
        float z = LOG2F(xhalf_add(vtsum(p)));
        f32x16 g;
#pragma unroll
        for (int i = 0; i < 16; ++i) g[i] = (LOG2F(p[i]) - z) * F_LN2;
        float* orow = &os[w][r][0];
        int cb = ((t & 3) << 5) + (h << 2);
        float4 v0 = {g[0],  g[1],  g[2],  g[3]};
        float4 v1 = {g[4],  g[5],  g[6],  g[7]};
        float4 v2 = {g[8],  g[9],  g[10], g[11]};
        float4 v3 = {g[12], g[13], g[14], g[15]};
        *(float4*)(orow + ((cb + 0)  ^ xr4)) = v0;
        *(float4*)(orow + ((cb + 8)  ^ xr4)) = v1;
        *(float4*)(orow + ((cb + 16) ^ xr4)) = v2;
        *(float4*)(orow + ((cb + 24) ^ xr4)) = v3;
        if ((t & 3) == 3) {
            __threadfence_block();
            int q_ = lane & 3, r2 = lane >> 2;
#pragma unroll
            for (int p_ = 0; p_ < 2; ++p_) {
                int rf = p_ * 16 + r2;
                const float* orf = &os[w][rf][0];
                float* gb = out + (size_t)(row0 + rf) * (SEQLEN * NSTATES)
                                + (size_t)(t - 3) * NSTATES;
#pragma unroll
                for (int k_ = 0; k_ < 8; ++k_) {
                    int L = (k_ << 4) + (q_ << 2);
                    *(float4*)(gb + L) = *(const float4*)(orf + (L ^ ((rf & 7) << 2)));
                }
            }
            __threadfence_block();
        }
    }
}

extern "C" void kernel_launch(void* const* d_in, const int* in_sizes, int n_in,
                              void* d_out, int out_size, void* d_ws, size_t ws_size,
                              hipStream_t stream) {
    const float* obvs     = (const float*)d_in[0];
    const float* log_init = (const float*)d_in[1];
    const float* Amat     = (const float*)d_in[2];
    const float* means    = (const float*)d_in[3];
    const float* log_sig  = (const float*)d_in[4];
    float* out = (float*)d_out;
    float* lfdump = (float*)d_ws;   // 128 MiB (ws >= 192 MiB established in r6/7)

    hipLaunchKernelGGL(hmm_recurse4, dim3(2048), dim3(128), 0, stream,
                       obvs, log_init, Amat, means, log_sig, lfdump, out);
    hipLaunchKernelGGL(hmm_combine3, dim3(2048), dim3(128), 0, stream,
                       lfdump, out);
}

// Round 11
// 114.538 us; speedup vs baseline: 1.6129x; 1.4692x over previous
//
#include <hip/hip_runtime.h>
#include <cstddef>

#define NSTATES 32
#define SEQLEN 4096
#define NBATCH 256
#define CHUNK 16
#define HALO 32
#define NCHUNKS 256                 // SEQLEN / CHUNK
#define SPAN_MAX 48                 // CHUNK + HALO

#define F_LOG2E 1.44269504088896340736f
#define F_LN2   0.69314718055994530942f
#define F_NEG_HALF_LOG2PI -0.91893853320467274178f
#define SCALE60 1.152921504606847e18f   // 2^60 on stored phi (r10-proven low-end regime)
#define SCALE30 1.073741824e9f          // 2^30 on stored b (headroom; cancels in z)

#define EXP2F(x) __builtin_amdgcn_exp2f(x)
#define LOG2F(x) __builtin_amdgcn_logf(x)   // v_log_f32 == log2, despite the name
#define RCPF(x)  __builtin_amdgcn_rcpf(x)

typedef __attribute__((ext_vector_type(8)))  short short8;
typedef __attribute__((ext_vector_type(16))) float f32x16;
typedef __attribute__((ext_vector_type(8)))  unsigned int uintv8;

static __device__ __forceinline__ unsigned int pkbf(float lo, float hi) {
    unsigned int r;
    asm("v_cvt_pk_bf16_f32 %0, %1, %2" : "=v"(r) : "v"(lo), "v"(hi));
    return r;
}
static __device__ __forceinline__ void swp32(unsigned int& a, unsigned int& b) {
    asm volatile("v_permlane32_swap_b32 %0, %1" : "+v"(a), "+v"(b));
}
static __device__ __forceinline__ float xhalf_max(float v) {
    float a = v, b;
    asm("v_mov_b32 %0, %1" : "=v"(b) : "v"(v));
    asm volatile("v_permlane32_swap_b32 %0, %1" : "+v"(a), "+v"(b));
    return fmaxf(a, b);
}
static __device__ __forceinline__ float xhalf_add(float v) {
    float a = v, b;
    asm("v_mov_b32 %0, %1" : "=v"(b) : "v"(v));
    asm volatile("v_permlane32_swap_b32 %0, %1" : "+v"(a), "+v"(b));
    return a + b;
}
static __device__ __forceinline__ float vtmax(const f32x16& d) {
    return fmaxf(
      fmaxf(fmaxf(fmaxf(d[0],d[1]),fmaxf(d[2],d[3])), fmaxf(fmaxf(d[4],d[5]),fmaxf(d[6],d[7]))),
      fmaxf(fmaxf(fmaxf(d[8],d[9]),fmaxf(d[10],d[11])), fmaxf(fmaxf(d[12],d[13]),fmaxf(d[14],d[15]))));
}
static __device__ __forceinline__ float vtsum(const f32x16& d) {
    return ((((d[0]+d[1])+(d[2]+d[3])) + ((d[4]+d[5])+(d[6]+d[7])))
          + (((d[8]+d[9])+(d[10]+d[11])) + ((d[12]+d[13])+(d[14]+d[15]))));
}
// B-frags use the SAME (h,e)->k map as the A-frags, so k-permutation cancels.
static __device__ __forceinline__ void make_frags(const f32x16& q, short8& lo, short8& hi) {
    unsigned int X  = pkbf(q[0],  q[1]),  Z  = pkbf(q[2],  q[3]);
    unsigned int Y  = pkbf(q[4],  q[5]),  W  = pkbf(q[6],  q[7]);
    unsigned int X2 = pkbf(q[8],  q[9]),  Z2 = pkbf(q[10], q[11]);
    unsigned int Y2 = pkbf(q[12], q[13]), W2 = pkbf(q[14], q[15]);
    swp32(X, Y); swp32(Z, W); swp32(X2, Y2); swp32(Z2, W2);
    union { unsigned int w[4]; short8 s; } u;
    u.w[0] = X;  u.w[1] = Z;  u.w[2] = Y;  u.w[3] = W;  lo = u.s;
    u.w[0] = X2; u.w[1] = Z2; u.w[2] = Y2; u.w[3] = W2; hi = u.s;
}

// bf16 dump slot (offset in ushort units; <<4 = 16 bf16 per lane per t)
#define DUMP_OFF(rg_, t_) ((((size_t)(rg_) * SEQLEN + (t_)) * 64 + lane) << 4)

#define MF_CONSTS_ALL                                                     \
    f32x16 muv, c0v, c1v, li2m;                                           \
    _Pragma("unroll")                                                     \
    for (int i = 0; i < 16; ++i) {                                        \
        int m = (i & 3) + ((i >> 2) << 3) + (h << 2);                     \
        float ls = log_sig[m];                                            \
        muv[i]  = means[m];                                               \
        c1v[i]  = -0.5f * expf(-2.0f * ls) * F_LOG2E;                     \
        c0v[i]  = (-ls + F_NEG_HALF_LOG2PI) * F_LOG2E;                    \
        li2m[i] = log_init[m] * F_LOG2E;                                  \
    }

#define MF_CONSTS_EMIT                                                    \
    f32x16 muv, c0v, c1v;                                                 \
    _Pragma("unroll")                                                     \
    for (int i = 0; i < 16; ++i) {                                        \
        int m = (i & 3) + ((i >> 2) << 3) + (h << 2);                     \
        float ls = log_sig[m];                                            \
        muv[i]  = means[m];                                               \
        c1v[i]  = -0.5f * expf(-2.0f * ls) * F_LOG2E;                     \
        c0v[i]  = (-ls + F_NEG_HALF_LOG2PI) * F_LOG2E;                    \
    }

#define MF_AFRAGS                                                         \
    const float* Ar = Amat + r * 32 + (h << 3);                           \
    float4 a0_ = *(const float4*)(Ar),      a1_ = *(const float4*)(Ar + 4);  \
    float4 a2_ = *(const float4*)(Ar + 16), a3_ = *(const float4*)(Ar + 20); \
    short8 alo, ahi;                                                      \
    {                                                                     \
        union { unsigned int ww[4]; short8 s; } ua;                       \
        ua.ww[0] = pkbf(a0_.x, a0_.y); ua.ww[1] = pkbf(a0_.z, a0_.w);     \
        ua.ww[2] = pkbf(a1_.x, a1_.y); ua.ww[3] = pkbf(a1_.z, a1_.w);     \
        alo = ua.s;                                                       \
        ua.ww[0] = pkbf(a2_.x, a2_.y); ua.ww[1] = pkbf(a2_.z, a2_.w);     \
        ua.ww[2] = pkbf(a3_.x, a3_.y); ua.ww[3] = pkbf(a3_.z, a3_.w);     \
        ahi = ua.s;                                                       \
    }

// stage obvs[row0+rr][tbase .. tbase+span) into xsw[t][rr]; tbase%4==0, span%4==0
#define MF_STAGE(xsw, tbase, span)                                        \
    {                                                                     \
        const float* xr_ = obvs + (size_t)(row0 + r) * SEQLEN + (tbase);  \
        for (int tt = 4 * h; tt + 4 <= (span); tt += 8) {                 \
            float4 v_ = *(const float4*)(xr_ + tt);                       \
            xsw[tt + 0][r] = v_.x; xsw[tt + 1][r] = v_.y;                 \
            xsw[tt + 2][r] = v_.z; xsw[tt + 3][r] = v_.w;                 \
        }                                                                 \
        __threadfence_block();                                            \
    }

// K1: fused fwd+bwd recursions; CHUNK=16, HALO=32, 4096 waves (4/SIMD).
// fwd waves store phi_t = d*rs (PRE-emission, *2^60) in bf16 to lfB.
// bwd waves store b_t = d*rs (*2^30) in bf16 to lbB. Combine adds emission.
__global__ __launch_bounds__(128, 4) void hmm_recurse5(
    const float* __restrict__ obvs, const float* __restrict__ log_init,
    const float* __restrict__ Amat, const float* __restrict__ means,
    const float* __restrict__ log_sig, unsigned short* __restrict__ lfB,
    unsigned short* __restrict__ lbB)
{
    __shared__ float xs[2][SPAN_MAX][32];
    const int tid = threadIdx.x;
    const int w = tid >> 6, lane = tid & 63, h = lane >> 5, r = lane & 31;
    const int wgid2 = blockIdx.x * 2 + w;
    const bool isfwd = (wgid2 < 2048);
    const int wgid = wgid2 & 2047;
    const int chunk = wgid & (NCHUNKS - 1);
    const int rg = wgid >> 8;
    const int row0 = rg << 5;

    MF_CONSTS_ALL;
    MF_AFRAGS;
    const f32x16 zro = (f32x16)0.0f;
    float (*xsw)[32] = xs[w];

    if (isfwd) {
        const int t0 = chunk * CHUNK, t1 = t0 + CHUNK;
        const int ts = (t0 > HALO) ? (t0 - HALO) : 0;
        MF_STAGE(xsw, ts, t1 - ts);
        f32x16 qh;
        {
            float x0 = xsw[0][r];
#pragma unroll
            for (int i = 0; i < 16; ++i) {
                float dx = x0 - muv[i];
                float cur = fmaf(c1v[i] * dx, dx, c0v[i]) + (ts == 0 ? li2m[i] : 0.0f);
                qh[i] = EXP2F(cur);
            }
            if (chunk == 0) {
                // phi_0 = normalized pi (f_0 = phi_0 * ev_0)
                f32x16 u;
#pragma unroll
                for (int i = 0; i < 16; ++i) u[i] = EXP2F(li2m[i]);
                float s = RCPF(xhalf_max(vtmax(u))) * SCALE60;
                uintv8 pk;
#pragma unroll
                for (int k = 0; k < 8; ++k) pk[k] = pkbf(u[2*k] * s, u[2*k+1] * s);
                *(uintv8*)(lfB + DUMP_OFF(rg, 0)) = pk;
            }
        }
        for (int t = ts + 1; t < t1; ++t) {
            short8 blo, bhi; make_frags(qh, blo, bhi);
            f32x16 d = __builtin_amdgcn_mfma_f32_32x32x16_bf16(alo, blo, zro, 0, 0, 0);
            d = __builtin_amdgcn_mfma_f32_32x32x16_bf16(ahi, bhi, d, 0, 0, 0);
            float rs = RCPF(xhalf_max(vtmax(d)));
            float x = xsw[t - ts][r];
            f32x16 phi;
#pragma unroll
            for (int i = 0; i < 16; ++i) {
                float dx = x - muv[i];
                float e2 = fmaf(c1v[i] * dx, dx, c0v[i]);
                phi[i] = d[i] * rs;
                qh[i] = phi[i] * EXP2F(e2);
            }
            if (t >= t0) {
                uintv8 pk;
#pragma unroll
                for (int k = 0; k < 8; ++k)
                    pk[k] = pkbf(phi[2*k] * SCALE60, phi[2*k+1] * SCALE60);
                *(uintv8*)(lfB + DUMP_OFF(rg, t)) = pk;
            }
        }
    } else {
        const int t0 = chunk * CHUNK, t1 = t0 + CHUNK;
        int tsb = t1 - 1 + HALO;
        if (tsb > SEQLEN - 1) tsb = SEQLEN - 1;
        MF_STAGE(xsw, t0, tsb - t0 + 1);
        f32x16 bh;
        if (tsb == SEQLEN - 1) {
            // exact init b(T-1) = exp2(li2m), max-normalized
            float lm = xhalf_max(vtmax(li2m));
#pragma unroll
            for (int i = 0; i < 16; ++i) bh[i] = EXP2F(li2m[i] - lm);
            if (chunk == NCHUNKS - 1) {
                uintv8 pk;
#pragma unroll
                for (int k = 0; k < 8; ++k)
                    pk[k] = pkbf(bh[2*k] * SCALE30, bh[2*k+1] * SCALE30);
                *(uintv8*)(lbB + DUMP_OFF(rg, SEQLEN - 1)) = pk;
            }
        } else {
#pragma unroll
            for (int i = 0; i < 16; ++i) bh[i] = 1.0f;
        }
        for (int t = tsb - 1; t >= t0; --t) {
            float x = xsw[t + 1 - t0][r];
            f32x16 wv;
#pragma unroll
            for (int i = 0; i < 16; ++i) {
                float dx = x - muv[i];
                float e2 = fmaf(c1v[i] * dx, dx, c0v[i]);
                wv[i] = bh[i] * EXP2F(e2);
            }
            short8 blo, bhi; make_frags(wv, blo, bhi);
            f32x16 d = __builtin_amdgcn_mfma_f32_32x32x16_bf16(alo, blo, zro, 0, 0, 0);
            d = __builtin_amdgcn_mfma_f32_32x32x16_bf16(ahi, bhi, d, 0, 0, 0);
            float rs = RCPF(xhalf_max(vtmax(d)));
#pragma unroll
            for (int i = 0; i < 16; ++i) bh[i] = d[i] * rs;
            if (t < t1) {
                uintv8 pk;
#pragma unroll
                for (int k = 0; k < 8; ++k)
                    pk[k] = pkbf(bh[2*k] * SCALE30, bh[2*k+1] * SCALE30);
                *(uintv8*)(lbB + DUMP_OFF(rg, t)) = pk;
            }
        }
    }
}

// K2: p = phi * b * ev (ev recomputed from obvs), z = log2(sum),
// out = (log2 p - z)*ln2; transpose via os tile, coalesced f32 writes.
__global__ __launch_bounds__(128) void hmm_combine4(
    const unsigned short* __restrict__ lfB, const unsigned short* __restrict__ lbB,
    const float* __restrict__ obvs, const float* __restrict__ means,
    const float* __restrict__ log_sig, float* __restrict__ out)
{
    __shared__ float os[2][32][128];
    const int tid = threadIdx.x;
    const int w = tid >> 6, lane = tid & 63, h = lane >> 5, r = lane & 31;
    const int wgid2 = blockIdx.x * 2 + w;          // [0,4096)
    const int rg = wgid2 >> 9, c8 = wgid2 & 511;
    const int row0 = rg << 5, tA = c8 << 3;
    const int xr4 = (r & 7) << 2;
    MF_CONSTS_EMIT;
    const float* xr = obvs + (size_t)(row0 + r) * SEQLEN;

    for (int tt = 0; tt < 8; ++tt) {
        int t = tA + tt;
        uintv8 Fw = *(const uintv8*)(lfB + DUMP_OFF(rg, t));
        uintv8 Bw = *(const uintv8*)(lbB + DUMP_OFF(rg, t));
        float x = xr[t];
        f32x16 p;
#pragma unroll
        for (int i = 0; i < 16; ++i) {
            unsigned int fw = Fw[i >> 1], bw = Bw[i >> 1];
            float fv = __int_as_float((i & 1) ? (fw & 0xffff0000u) : (fw << 16));
            float bv = __int_as_float((i & 1) ? (bw & 0xffff0000u) : (bw << 16));
            float dx = x - muv[i];
            float ev = EXP2F(fmaf(c1v[i] * dx, dx, c0v[i]));
            p[i] = fv * bv * ev;
        }
        float z = LOG2F(xhalf_add(vtsum(p)));
        f32x16 g;
#pragma unroll
        for (int i = 0; i < 16; ++i) g[i] = (LOG2F(p[i]) - z) * F_LN2;
        float* orow = &os[w][r][0];
        int cb = ((t & 3) << 5) + (h << 2);
        float4 v0 = {g[0],  g[1],  g[2],  g[3]};
        float4 v1 = {g[4],  g[5],  g[6],  g[7]};
        float4 v2 = {g[8],  g[9],  g[10], g[11]};
        float4 v3 = {g[12], g[13], g[14], g[15]};
        *(float4*)(orow + ((cb + 0)  ^ xr4)) = v0;
        *(float4*)(orow + ((cb + 8)  ^ xr4)) = v1;
        *(float4*)(orow + ((cb + 16) ^ xr4)) = v2;
        *(float4*)(orow + ((cb + 24) ^ xr4)) = v3;
        if ((t & 3) == 3) {
            __threadfence_block();
            int q_ = lane & 3, r2 = lane >> 2;
#pragma unroll
            for (int p_ = 0; p_ < 2; ++p_) {
                int rf = p_ * 16 + r2;
                const float* orf = &os[w][rf][0];
                float* gb = out + (size_t)(row0 + rf) * (SEQLEN * NSTATES)
                                + (size_t)(t - 3) * NSTATES;
#pragma unroll
                for (int k_ = 0; k_ < 8; ++k_) {
                    int L = (k_ << 4) + (q_ << 2);
                    *(float4*)(gb + L) = *(const float4*)(orf + (L ^ ((rf & 7) << 2)));
                }
            }
            __threadfence_block();
        }
    }
}

extern "C" void kernel_launch(void* const* d_in, const int* in_sizes, int n_in,
                              void* d_out, int out_size, void* d_ws, size_t ws_size,
                              hipStream_t stream) {
    const float* obvs     = (const float*)d_in[0];
    const float* log_init = (const float*)d_in[1];
    const float* Amat     = (const float*)d_in[2];
    const float* means    = (const float*)d_in[3];
    const float* log_sig  = (const float*)d_in[4];
    float* out = (float*)d_out;

    const size_t NE = (size_t)NBATCH * SEQLEN * NSTATES;   // 33.5M
    unsigned short* lfB = (unsigned short*)d_ws;           // 67 MB
    unsigned short* lbB = lfB + NE;                        // 67 MB (ws >= 192 MB, est. r6/7)

    hipLaunchKernelGGL(hmm_recurse5, dim3(2048), dim3(128), 0, stream,
                       obvs, log_init, Amat, means, log_sig, lfB, lbB);
    hipLaunchKernelGGL(hmm_combine4, dim3(2048), dim3(128), 0, stream,
                       lfB, lbB, obvs, means, log_sig, out);
}